// Round 6
// baseline (75.688 us; speedup 1.0000x reference)
//
#include <hip/hip_runtime.h>
#include <hip/hip_fp16.h>

// VoxelProjection_fish — two-phase:
//  (A) transpose input [C][P] f32 -> T2 [P][336] f16 (unpadded 672B rows)
//  (B) per-voxel 16B-granule gather w/ register prefetch + LDS transpose + NT store.

#define C_IN  336
#define ZB    6
#define BEV_H 240
#define BEV_W 120
#define LVOX  (ZB * BEV_H * BEV_W)   // 172800
#define HF    160
#define WF    256
#define PIX   (HF * WF)              // 40960
#define HW    (BEV_H * BEV_W)        // 28800
#define ROWH  336                    // halves per T2 row (672 B; 672%16==0)

typedef float f32x4 __attribute__((ext_vector_type(4)));   // NT-store-compatible

// ---------- Kernel A: transpose input [C_IN][PIX] f32 -> T2 [PIX][ROWH] f16 ----------
#define TA_P 64
#define TA_C 48   // 336 = 7 * 48
__global__ __launch_bounds__(256) void transpose_f16_kernel(
    const float* __restrict__ in, __half* __restrict__ T2)
{
    __shared__ float tile[TA_C][TA_P + 1];
    const int p0 = blockIdx.x * TA_P;
    const int c0 = blockIdx.y * TA_C;
    const int t  = threadIdx.x;

    #pragma unroll
    for (int i = 0; i < (TA_P * TA_C) / 256; ++i) {   // 12
        int idx = i * 256 + t;
        int cl = idx >> 6;
        int pl = idx & 63;
        tile[cl][pl] = __builtin_nontemporal_load(
            &in[(size_t)(c0 + cl) * PIX + p0 + pl]);   // coalesced 256B rows, read-once
    }
    __syncthreads();
    #pragma unroll
    for (int i = 0; i < (TA_P * TA_C / 2) / 256; ++i) {   // 6: one half2 per thread
        int idx = i * 256 + t;
        int cl2 = idx % (TA_C / 2);     // 0..23
        int pl  = idx / (TA_C / 2);
        __half2 hv = __floats2half2_rn(tile[2 * cl2][pl], tile[2 * cl2 + 1][pl]);
        *reinterpret_cast<__half2*>(
            &T2[(size_t)(p0 + pl) * ROWH + c0 + 2 * cl2]) = hv;   // 96B contiguous per 24 lanes
    }
}

// ---------- Kernel B: 16B-granule gather, weight, LDS transpose, NT store ----------
#define VB   64                // voxels per block (64 | 28800 -> z uniform)
#define CC   112               // channels per chunk (336 = 3 * 112)
#define NCH  (C_IN / CC)       // 3
#define LROW (VB + 1)          // 65 floats: phase-3 b32 reads 2-way max (free)
#define GPV  (CC / 8)          // 14 uint4 granules per voxel-chunk
#define GPC  (VB * GPV)        // 896 granules per chunk; 896 = 3.5*256 -> threads<128 take 4

__global__ __launch_bounds__(256) void gather_f16_kernel(
    const __half* __restrict__ T2,
    const int*    __restrict__ uu,
    const int*    __restrict__ vv,
    const float*  __restrict__ valid,
    const float*  __restrict__ density,
    float*        __restrict__ out)
{
    __shared__ float tile[CC * LROW];   // 29.1 KB -> 5 blocks/CU
    __shared__ int   p_s[VB];
    __shared__ float w_s[VB];

    const int t   = threadIdx.x;
    const int l0  = blockIdx.x * VB;
    const int z   = l0 / HW;            // wave-uniform
    const int hw0 = l0 - z * HW;

    if (t < VB) {
        int l = l0 + t;
        p_s[t] = vv[l] * WF + uu[l];
        w_s[t] = valid[l] * density[l];
    }
    __syncthreads();

    // Fixed per-thread (voxel, granule) assignment. i==3 only for t<128 (wave-uniform).
    int   qg[4];
    float qw[4];
    const __half* qbase[4];
    #pragma unroll
    for (int i = 0; i < 4; ++i) {
        if (i < 3 || t < 128) {
            int q = i * 256 + t;          // < 896
            int v = q / GPV;
            qg[i] = q - v * GPV;
            qw[i] = w_s[v];
            qbase[i] = T2 + (size_t)p_s[v] * ROWH + qg[i] * 8;   // 16B-aligned
        }
    }

    // Prefetch chunk 0 into regs (16B scattered loads).
    uint4 pf[4];
    #pragma unroll
    for (int i = 0; i < 4; ++i)
        if (i < 3 || t < 128)
            pf[i] = *reinterpret_cast<const uint4*>(qbase[i]);

    #pragma unroll
    for (int ch = 0; ch < NCH; ++ch) {
        // Unpack + weight -> LDS [c][v]
        #pragma unroll
        for (int i = 0; i < 4; ++i) {
            if (i < 3 || t < 128) {
                int q = i * 256 + t;
                int v = q / GPV;           // recompute (cheap) to keep reg pressure low
                const float2 f0 = __half22float2(*reinterpret_cast<const __half2*>(&pf[i].x));
                const float2 f1 = __half22float2(*reinterpret_cast<const __half2*>(&pf[i].y));
                const float2 f2 = __half22float2(*reinterpret_cast<const __half2*>(&pf[i].z));
                const float2 f3 = __half22float2(*reinterpret_cast<const __half2*>(&pf[i].w));
                const float w = qw[i];
                int base = (qg[i] * 8) * LROW + v;
                tile[base]          = f0.x * w;
                tile[base + LROW]   = f0.y * w;
                tile[base + 2*LROW] = f1.x * w;
                tile[base + 3*LROW] = f1.y * w;
                tile[base + 4*LROW] = f2.x * w;
                tile[base + 5*LROW] = f2.y * w;
                tile[base + 6*LROW] = f3.x * w;
                tile[base + 7*LROW] = f3.y * w;
            }
        }
        __syncthreads();

        // T14: issue next chunk's gathers now; in flight through the store phase.
        if (ch + 1 < NCH) {
            #pragma unroll
            for (int i = 0; i < 4; ++i)
                if (i < 3 || t < 128)
                    pf[i] = *reinterpret_cast<const uint4*>(qbase[i] + (ch + 1) * CC);
        }

        // Store phase: per channel-row, 16 lanes x f32x4 = 256B coalesced NT stores.
        {
            const int vq = (t & 15) * 4;
            const int cb = t >> 4;
            #pragma unroll
            for (int i2 = 0; i2 < CC / 16; ++i2) {   // 7
                int cl = i2 * 16 + cb;
                f32x4 o;
                o.x = tile[cl * LROW + vq + 0];
                o.y = tile[cl * LROW + vq + 1];
                o.z = tile[cl * LROW + vq + 2];
                o.w = tile[cl * LROW + vq + 3];
                __builtin_nontemporal_store(o, reinterpret_cast<f32x4*>(
                    &out[(size_t)(z * C_IN + ch * CC + cl) * HW + hw0 + vq]));
            }
        }
        __syncthreads();
    }
}

// ---------- Fallback: direct scattered gather (round-1 kernel) ----------
#define CPT 16
__global__ __launch_bounds__(256) void voxel_proj_direct(
    const float* __restrict__ input,
    const int*   __restrict__ uu,
    const int*   __restrict__ vv,
    const float* __restrict__ valid,
    const float* __restrict__ density,
    float*       __restrict__ out)
{
    const int l = blockIdx.x * 256 + threadIdx.x;
    const int p = vv[l] * WF + uu[l];
    const float w = valid[l] * density[l];
    const int z  = l / HW;
    const int hw = l - z * HW;
    const float* inb  = input + p;
    float*       outb = out + (size_t)z * C_IN * HW + hw;
    const int c0 = blockIdx.y * CPT;
    #pragma unroll
    for (int i = 0; i < CPT; ++i) {
        const int c = c0 + i;
        outb[(size_t)c * HW] = inb[(size_t)c * PIX] * w;
    }
}

extern "C" void kernel_launch(void* const* d_in, const int* in_sizes, int n_in,
                              void* d_out, int out_size, void* d_ws, size_t ws_size,
                              hipStream_t stream)
{
    const float* input   = (const float*)d_in[0];
    const int*   uu      = (const int*)  d_in[1];
    const int*   vv      = (const int*)  d_in[2];
    const float* valid   = (const float*)d_in[3];
    const float* density = (const float*)d_in[4];
    float*       out     = (float*)d_out;

    const size_t T_bytes = (size_t)PIX * ROWH * sizeof(__half);   // 27.6 MB
    if (ws_size >= T_bytes) {
        __half* T2 = (__half*)d_ws;
        transpose_f16_kernel<<<dim3(PIX / TA_P, C_IN / TA_C), dim3(256), 0, stream>>>(input, T2);
        gather_f16_kernel<<<dim3(LVOX / VB), dim3(256), 0, stream>>>(T2, uu, vv, valid, density, out);
    } else {
        voxel_proj_direct<<<dim3(LVOX / 256, C_IN / CPT), dim3(256), 0, stream>>>(
            input, uu, vv, valid, density, out);
    }
}